// Round 1
// baseline (68.196 us; speedup 1.0000x reference)
//
#include <hip/hip_runtime.h>

// x = q @ inv(I + a0*eye(k=T0) + a1*eye(k=T1))  ==>  x[j] = q[j] - a0*x[j-T0] - a1*x[j-T1]
// loss = sum(x[0,0,-T1:]**2). Only q[0,0,:] matters.

#define LENGTH 8137
#define T0 844
#define T1 1264

__global__ __launch_bounds__(256) void iir_loss_kernel(const float* __restrict__ q,
                                                       const float* __restrict__ alpha0,
                                                       const float* __restrict__ alpha1,
                                                       float* __restrict__ out) {
    __shared__ float x[LENGTH];
    __shared__ float partial[4];

    const float a0 = alpha0[0];
    const float a1 = alpha1[0];
    const int tid = threadIdx.x;

    // Chunked recurrence: chunk c covers [c*T0, min((c+1)*T0, LENGTH)).
    // For j in chunk c: j-T0 is in chunk c-1, j-T1 is in chunk <= c-1
    // (T1 > T0), so with a barrier per chunk all deps are ready.
    const int nchunks = (LENGTH + T0 - 1) / T0;  // 10
    for (int c = 0; c < nchunks; ++c) {
        const int start = c * T0;
        const int end = (start + T0 < LENGTH) ? (start + T0) : LENGTH;
        for (int j = start + tid; j < end; j += 256) {
            float v = q[j];                      // q[0,0,j] — first row of (4,8,L)
            if (j >= T0) v -= a0 * x[j - T0];
            if (j >= T1) v -= a1 * x[j - T1];
            x[j] = v;
        }
        __syncthreads();
    }

    // loss = sum over j in [LENGTH-T1, LENGTH) of x[j]^2
    float s = 0.f;
    for (int j = (LENGTH - T1) + tid; j < LENGTH; j += 256) {
        s += x[j] * x[j];
    }
    // 64-lane wave reduction
    for (int off = 32; off > 0; off >>= 1)
        s += __shfl_down(s, off, 64);
    const int wave = tid >> 6;
    if ((tid & 63) == 0) partial[wave] = s;
    __syncthreads();
    if (tid == 0) {
        float tot = partial[0] + partial[1] + partial[2] + partial[3];
        out[0] = tot;
    }
}

extern "C" void kernel_launch(void* const* d_in, const int* in_sizes, int n_in,
                              void* d_out, int out_size, void* d_ws, size_t ws_size,
                              hipStream_t stream) {
    const float* q      = (const float*)d_in[0];   // (4, 8, 8137) f32; only [0,0,:] used
    const float* alpha0 = (const float*)d_in[1];   // scalar
    const float* alpha1 = (const float*)d_in[2];   // scalar
    float* out = (float*)d_out;                    // 1 element f32

    iir_loss_kernel<<<1, 256, 0, stream>>>(q, alpha0, alpha1, out);
}

// Round 2
// 59.806 us; speedup vs baseline: 1.1403x; 1.1403x over previous
//
#include <hip/hip_runtime.h>

// Reference: x = q @ inv(I + a0*eye(k=T0) + a1*eye(k=T1)); loss = sum(x[0,0,-T1:]^2).
// A' = a0*E(T0)+a1*E(T1) is nilpotent => closed form:
//   x[j] = sum_{m,n>=0, 844m+1264n <= j} (-1)^{m+n} C(m+n,m) a0^m a1^n q[j-844m-1264n]
// Only q[0,0,:] and the last T1 outputs matter. Fully parallel, no recurrence.

#define LENGTH 8137
#define T0 844
#define T1 1264
#define JSTART (LENGTH - T1)   // 6873, first needed output index
#define MMAX 9                 // 844*9  = 7596 <= 8136
#define NMAX 6                 // 1264*6 = 7584 <= 8136

__global__ __launch_bounds__(256) void iir_loss_kernel(const float* __restrict__ q,
                                                       const float* __restrict__ a0p,
                                                       const float* __restrict__ a1p,
                                                       float* __restrict__ out) {
    __shared__ float xq[LENGTH];
    __shared__ float coef[NMAX + 1][MMAX + 1];
    __shared__ float partial[4];

    const int tid = threadIdx.x;
    const float a0 = a0p[0];
    const float a1 = a1p[0];

    // ---- Stage q[0,0,:] into LDS, vectorized (2034 float4 + 1 tail) ----
    const float4* q4 = reinterpret_cast<const float4*>(q);
    for (int i = tid; i < LENGTH / 4; i += 256) {
        float4 v = q4[i];
        xq[4 * i + 0] = v.x;
        xq[4 * i + 1] = v.y;
        xq[4 * i + 2] = v.z;
        xq[4 * i + 3] = v.w;
    }
    if (tid == 0) {
        xq[LENGTH - 1] = q[LENGTH - 1];
        // ---- Coefficient table: coef[n][m] = (-1)^{m+n} C(m+n,m) a0^m a1^n ----
        // Pascal recurrence: c[n][m] = -a0*c[n][m-1] - a1*c[n-1][m]
        coef[0][0] = 1.f;
        for (int m = 1; m <= MMAX; ++m) coef[0][m] = -a0 * coef[0][m - 1];
        for (int n = 1; n <= NMAX; ++n) {
            coef[n][0] = -a1 * coef[n - 1][0];
            for (int m = 1; m <= MMAX; ++m)
                coef[n][m] = -a0 * coef[n][m - 1] - a1 * coef[n - 1][m];
        }
    }
    __syncthreads();

    // ---- Each thread computes outputs j = JSTART + tid + 256*k, k = 0..4 ----
    // (1264 outputs; k=4 only for tid < 240). (m,n) outer so each coef is one
    // LDS broadcast read reused across the 5 statically-indexed accumulators.
    float v0 = 0.f, v1 = 0.f, v2 = 0.f, v3 = 0.f, v4 = 0.f;
    const int j0 = JSTART + tid;
    const bool has4 = (tid < (T1 - 4 * 256));  // 240

    for (int n = 0; n <= NMAX; ++n) {
        const int sn = T1 * n;
        for (int m = 0; m <= MMAX; ++m) {
            const int shift = sn + T0 * m;
            if (shift >= LENGTH) break;
            const float c = coef[n][m];
            const int off = j0 - shift;
            if (off >= 0)                 v0 += c * xq[off];
            if (off + 256 >= 0)           v1 += c * xq[off + 256];
            if (off + 512 >= 0)           v2 += c * xq[off + 512];
            if (off + 768 >= 0)           v3 += c * xq[off + 768];
            if (has4 && off + 1024 >= 0)  v4 += c * xq[off + 1024];
        }
    }

    float s = v0 * v0 + v1 * v1 + v2 * v2 + v3 * v3 + v4 * v4;

    // ---- Block reduction: 64-lane wave shuffle, then 4 partials ----
    for (int off = 32; off > 0; off >>= 1)
        s += __shfl_down(s, off, 64);
    if ((tid & 63) == 0) partial[tid >> 6] = s;
    __syncthreads();
    if (tid == 0)
        out[0] = partial[0] + partial[1] + partial[2] + partial[3];
}

extern "C" void kernel_launch(void* const* d_in, const int* in_sizes, int n_in,
                              void* d_out, int out_size, void* d_ws, size_t ws_size,
                              hipStream_t stream) {
    const float* q      = (const float*)d_in[0];  // (4, 8, 8137) f32; only [0,0,:]
    const float* alpha0 = (const float*)d_in[1];  // scalar
    const float* alpha1 = (const float*)d_in[2];  // scalar
    float* out = (float*)d_out;                   // 1 element f32

    iir_loss_kernel<<<1, 256, 0, stream>>>(q, alpha0, alpha1, out);
}

// Round 4
// 59.593 us; speedup vs baseline: 1.1444x; 1.0036x over previous
//
#include <hip/hip_runtime.h>

// Reference: x = q @ inv(I + a0*eye(k=T0) + a1*eye(k=T1)); loss = sum(x[0,0,-T1:]^2).
// A' = a0*E(T0)+a1*E(T1) is nilpotent => closed form:
//   x[j] = sum_{m,n>=0, 844m+1264n <= j} (-1)^{m+n} C(m+n,m) a0^m a1^n q[j-844m-1264n]
// Only q[0,0,:] and the last T1 outputs matter. 40 valid (m,n) terms.
// Single block, 1024 threads (16 waves on one CU): thread t computes
// j = 6873+t, and j = 7897+t for t < 240. Coef table built redundantly
// in registers (fully unrolled => static indexing, compile-time shifts).

#define LENGTH 8137
#define T0 844
#define T1 1264
#define JSTART (LENGTH - T1)   // 6873
#define MMAX 9
#define NMAX 6
#define NT 1024

__global__ __launch_bounds__(1024) void iir_loss_kernel(const float* __restrict__ q,
                                                        const float* __restrict__ a0p,
                                                        const float* __restrict__ a1p,
                                                        float* __restrict__ out) {
    __shared__ float xq[LENGTH];
    __shared__ float partial[16];

    const int tid = threadIdx.x;

    // ---- Stage q[0,0,:] into LDS (2034 float4 + 1 tail) ----
    const float4* q4 = reinterpret_cast<const float4*>(q);
    for (int i = tid; i < LENGTH / 4; i += NT) {
        float4 v = q4[i];
        xq[4 * i + 0] = v.x;
        xq[4 * i + 1] = v.y;
        xq[4 * i + 2] = v.z;
        xq[4 * i + 3] = v.w;
    }
    if (tid == NT - 1) xq[LENGTH - 1] = q[LENGTH - 1];

    // ---- Coef table in registers (redundant per thread, fully unrolled) ----
    // coef[n][m] = (-1)^{m+n} C(m+n,m) a0^m a1^n via Pascal recurrence.
    const float a0 = a0p[0];
    const float a1 = a1p[0];
    float coef[NMAX + 1][MMAX + 1];
    coef[0][0] = 1.f;
#pragma unroll
    for (int m = 1; m <= MMAX; ++m) coef[0][m] = -a0 * coef[0][m - 1];
#pragma unroll
    for (int n = 1; n <= NMAX; ++n) {
        coef[n][0] = -a1 * coef[n - 1][0];
#pragma unroll
        for (int m = 1; m <= MMAX; ++m)
            coef[n][m] = -a0 * coef[n][m - 1] - a1 * coef[n - 1][m];
    }

    __syncthreads();

    // ---- Outputs: j0 = JSTART+tid (all), j1 = j0+1024 (tid < 240) ----
    const int j0 = JSTART + tid;
    const bool has1 = (tid < (T1 - NT));  // 240
    float v0 = 0.f, v1 = 0.f;

#pragma unroll
    for (int n = 0; n <= NMAX; ++n) {
#pragma unroll
        for (int m = 0; m <= MMAX; ++m) {
            const int shift = T1 * n + T0 * m;     // compile-time after unroll
            if (shift >= LENGTH) continue;          // prunes to 40 live terms
            const float c = coef[n][m];
            const int off = j0 - shift;
            if (off >= 0)                 v0 += c * xq[off];
            if (has1 && off + NT >= 0)    v1 += c * xq[off + NT];
        }
    }

    float s = v0 * v0 + v1 * v1;  // v1 == 0 unless has1

    // ---- Block reduction: 16 waves ----
    for (int off = 32; off > 0; off >>= 1)
        s += __shfl_down(s, off, 64);
    if ((tid & 63) == 0) partial[tid >> 6] = s;
    __syncthreads();
    if (tid < 64) {
        float t = (tid < 16) ? partial[tid] : 0.f;
        for (int off = 8; off > 0; off >>= 1)
            t += __shfl_down(t, off, 64);
        if (tid == 0) out[0] = t;
    }
}

extern "C" void kernel_launch(void* const* d_in, const int* in_sizes, int n_in,
                              void* d_out, int out_size, void* d_ws, size_t ws_size,
                              hipStream_t stream) {
    const float* q      = (const float*)d_in[0];  // (4, 8, 8137) f32; only [0,0,:]
    const float* alpha0 = (const float*)d_in[1];  // scalar
    const float* alpha1 = (const float*)d_in[2];  // scalar
    float* out = (float*)d_out;                   // 1 element f32

    iir_loss_kernel<<<1, NT, 0, stream>>>(q, alpha0, alpha1, out);
}